// Round 7
// baseline (284.781 us; speedup 1.0000x reference)
//
#include <hip/hip_runtime.h>
#include <hip/hip_bf16.h>
#include <cstdint>

// ---------------------------------------------------------------------------
#define IMGSZ 224
#define OUTSZ 112
#define POOLSZ 56
#define OCN 128
#define BN_ 32
#define PIX1 (OUTSZ*OUTSZ)     // 12544
#define PIX2 (POOLSZ*POOLSZ)   // 3136
#define HP 58                  // padded pooled dim (56 + 2)
#define HSTRIDE (HP*HP*OCN)    // elems per n in h2p
#define PW 240                 // padded input row stride (x in [-3,236))
#define PH 233                 // padded input rows (y in [-3,230))
#define PPL (PH*PW)            // 55920 elems per padded plane
#define K1C 192                // conv1 K: 24 groups of 8 = (ic*7+ky)*8+kx layout

typedef float f32x4 __attribute__((ext_vector_type(4)));
typedef short bf16x8 __attribute__((ext_vector_type(8)));
struct alignas(4) u4a { unsigned x, y, z, w; };   // 4B-aligned 16B load

__device__ inline short f2bf(float v) {
    __hip_bfloat16 h = __float2bfloat16(v);
    return *(short*)&h;
}
__device__ inline unsigned pack2bf(float a, float b) {
    return (unsigned short)f2bf(a) | ((unsigned)(unsigned short)f2bf(b) << 16);
}
__device__ inline float bf2f(short s) {
    return __uint_as_float(((unsigned)(unsigned short)s) << 16);
}
__device__ inline bf16x8 ldb8(const short* p) {   // 16B load, 4B-aligned
    u4a t = *(const u4a*)p;
    union { u4a u; bf16x8 v; } c; c.u = t; return c.v;
}
__device__ inline void gload16(const short* g, short* l) {   // async global->LDS, 16B/lane
    __builtin_amdgcn_global_load_lds((const __attribute__((address_space(1))) void*)g,
                                     (__attribute__((address_space(3))) void*)l, 16, 0, 0);
}

// DPP 16-lane sum: quad_perm xor1, xor2, row_half_mirror, row_mirror.
// Pure VALU — replaces the 4-step ds_swizzle butterfly (DS pipe relief).
template<int CTRL>
__device__ inline float dppf(float v) {
    return __int_as_float(__builtin_amdgcn_update_dpp(0, __float_as_int(v), CTRL, 0xF, 0xF, true));
}
__device__ inline float rowsum16(float v) {
    v += dppf<0xB1>(v);    // quad_perm [1,0,3,2]  (xor 1)
    v += dppf<0x4E>(v);    // quad_perm [2,3,0,1]  (xor 2)
    v += dppf<0x141>(v);   // row_half_mirror      (8-group sum)
    v += dppf<0x140>(v);   // row_mirror           (16-group sum)
    return v;              // all 16 lanes of each row hold the 16-sum
}

// ---------------------------------------------------------------------------
// Fused setup + pad: [0,49) map ; [49,145) wpack1 ; [145,721) wconv2 pack ;
// [721,785) stats zero ; [785,2609) h2p halo zero ; [2609,24977) input pad.
// wconv2 pack: w2b holds 18 K-step tiles (t = s*2 + ic_half), each the EXACT
// 16 KB LDS image: [oc 128][8 chunks of 16B], chunk slot = (ic6>>3) ^ (oc&7).
// pad: zero-haloed bf16 input, TWO copies: padA[x]=img[x-3], padB[x]=img[x-2].
__global__ __launch_bounds__(256) void k_setup(const float* __restrict__ w1,
                                               short* __restrict__ w1b,
                                               const float* __restrict__ w2,
                                               short* __restrict__ w2b,
                                               int2* __restrict__ map,
                                               float* __restrict__ stats,
                                               unsigned* __restrict__ h2p,
                                               const float* __restrict__ inp,
                                               short* __restrict__ padA,
                                               short* __restrict__ padB) {
    int blk = blockIdx.x;
    int tid = threadIdx.x;
    if (blk >= 2609) {                    // pad section: 22368 blocks
        int idx = blk - 2609;
        int pl = idx / PH, y = idx - (idx / PH) * PH;
        int x = tid;
        if (x >= PW) return;
        int iy = y - 3;
        bool yok = (unsigned)iy < 224u;
        const float* src = inp + (size_t)pl * 50176 + iy * 224;
        float vA = (yok && (unsigned)(x - 3) < 224u) ? src[x - 3] : 0.f;
        float vB = (yok && (unsigned)(x - 2) < 224u) ? src[x - 2] : 0.f;
        size_t o = (size_t)pl * PPL + y * PW + x;
        padA[o] = f2bf(vA);
        padB[o] = f2bf(vB);
        return;
    }
    if (blk < 49) {
        int p = blk * 256 + tid;
        int oy = p / OUTSZ, ox = p % OUTSZ;
        int e = min(min(oy, ox), min(111 - oy, 111 - ox));
        int s = e >> 3;
        int a = 16 * s, b = a + 16, c = 224 - b, d = 224 - a;
        int ao = a >> 1, bo = b >> 1, co = c >> 1, dd = d >> 1;
        int ti, li, bi, ri;
        if      (oy >= ao && oy < bo && ox >= ao && ox < co) { ti=a; li=a; bi=b; ri=c; }
        else if (oy >= bo && oy < dd && ox >= ao && ox < bo) { ti=b; li=a; bi=d; ri=b; }
        else if (oy >= co && oy < dd && ox >= bo && ox < dd) { ti=c; li=b; bi=d; ri=d; }
        else                                                 { ti=a; li=c; bi=c; ri=d; }
        float scale = (float)(2.0 - (double)s * 0.16666666666666666);
        int tip = (int)((float)(ti + 6) / scale) - 3;
        int lip = (int)((float)(li + 6) / scale) - 3;
        int bip = (int)((float)(bi + 6) / scale) + 3;
        int rip = (int)((float)(ri + 6) / scale) + 3;
        int fh = (bip - tip - 7) / 2 + 1;
        int fw = (rip - lip - 7) / 2 + 1;
        int to = ti >> 1, lo = li >> 1, bo2 = bi >> 1, ro = ri >> 1;
        int i = oy - to, j = ox - lo;
        int pp = (i * fh) / (bo2 - to);
        int qq = (j * fw) / (ro - lo);
        map[p] = make_int2(tip + 2 * pp, lip + 2 * qq);
    } else if (blk < 145) {
        int idx = (blk - 49) * 256 + tid;
        int oc = idx / K1C, k = idx % K1C;
        int g8 = k >> 3, e2 = k & 7;
        float v = 0.f;
        if (g8 < 21 && e2 < 7) {
            int ic = g8 / 7, ky = g8 - ic * 7;
            v = w1[((oc * 3 + ic) * 7 + ky) * 7 + e2];
        }
        w1b[idx] = f2bf(v);
    } else if (blk < 721) {
        int idx = (blk - 145) * 256 + tid;      // input element of w2 (OIHW flat)
        int oc = idx / 1152;
        int rem = idx - oc * 1152;
        int ic = rem / 9;
        int s  = rem - ic * 9;
        int t  = s * 2 + (ic >> 6);             // K-step
        int ic6 = ic & 63;
        int slot = (ic6 >> 3) ^ (oc & 7);       // XOR-swizzled 16B chunk slot
        w2b[t * 8192 + oc * 64 + slot * 8 + (ic6 & 7)] = f2bf(w2[idx]);
    } else if (blk < 785) {
        stats[(blk - 721) * 256 + tid] = 0.f;
    } else {
        int idx = blk - 785;                  // 0..1823
        int bx = idx % 57, n = idx / 57;
        int c2 = tid & 63, po = tid >> 6;
        int pp = bx * 4 + po;                 // 0..227
        int y, x;
        if      (pp < 58)  { y = 0;  x = pp; }
        else if (pp < 116) { y = 57; x = pp - 58; }
        else if (pp < 172) { y = pp - 116 + 1; x = 0; }
        else               { y = pp - 172 + 1; x = 57; }
        h2p[(size_t)n * (HSTRIDE / 2) + (y * HP + x) * 64 + c2] = 0u;
    }
}

// ---------------------------------------------------------------------------
// conv1 v6: r4 geometry (wave = 64 oc x 32 px; block = 4 waves = 128 px; XCD
// n-chunked grid; 4 blocks/CU — the write-combining sweet spot, see r2/r5
// post-mortems). Delta vs r4: A fragments are loaded DIRECTLY from global
// w1b (24 KB slice, L1-resident, per-lane base + constant offsets) — no LDS
// staging, no pre-MFMA barrier, no ds_read conflicts; DS pipe freed entirely
// (LDS = 2 KB sred only). B = 12 up-front global 16B im2col gathers.
// Stats via DPP rowsum (VALU).
__global__ __launch_bounds__(256, 4) void k_conv1m(const short* __restrict__ padA,
                                                   const short* __restrict__ padB,
                                                   const short* __restrict__ w1b,
                                                   const int2* __restrict__ map,
                                                   short* __restrict__ out1b,
                                                   float* __restrict__ sum1x,
                                                   float* __restrict__ sq1x) {
    __shared__ float sred[4][64][2];   // 2 KB
    int tid = threadIdx.x;
    int wave = tid >> 6, lane = tid & 63;
    int q = lane >> 4, l16 = lane & 15;
    // XCD-chunked id remap: 6272 = 8 XCD x 784; 784 = 4 images x 196 blocks.
    int id = blockIdx.x;
    int swz = (id & 7) * 784 + (id >> 3);
    int n = swz / 196;
    int x196 = swz - n * 196;
    int ochalf = x196 & 1;
    int pxblk = x196 >> 1;                            // 0..97
    int px0 = pxblk * 128 + wave * 32 + l16;
    int px1 = px0 + 16;
    int2 m0 = map[px0];
    int2 m1 = map[px1];
    size_t bn = (size_t)n * 3 * PPL;
    const short* r0 = ((m0.y & 1) ? padB + (m0.y - 1) : padA + m0.y) + bn + m0.x * PW;
    const short* r1 = ((m1.y & 1) ? padB + (m1.y - 1) : padA + m1.y) + bn + m1.x * PW;

    // B gathers up-front (longest latency; consumed in-order by MFMA loop)
    bf16x8 ld[12];
#pragma unroll
    for (int icc = 0; icc < 6; icc++) {
        int g8 = (icc == 5) ? 20 : (icc * 4 + q);
        int ic = (g8 >= 7) + (g8 >= 14);
        int ky = g8 - ic * 7;
        int off = ic * PPL + ky * PW;
        ld[icc * 2]     = ldb8(r0 + off);
        ld[icc * 2 + 1] = ldb8(r1 + off);
    }

    // per-lane A base: row = t*16 + l16 (oc_local), chunk = icc*4 + q.
    const short* wsl = w1b + ochalf * 64 * K1C + l16 * K1C + q * 8;

    f32x4 acc[4][2];
#pragma unroll
    for (int t = 0; t < 4; t++) { acc[t][0] = (f32x4){0,0,0,0}; acc[t][1] = (f32x4){0,0,0,0}; }

#pragma unroll
    for (int icc = 0; icc < 6; icc++) {
        bf16x8 bf0 = ld[icc * 2];
        bf16x8 bf1 = ld[icc * 2 + 1];
#pragma unroll
        for (int t = 0; t < 4; t++) {
            bf16x8 af = ldb8(wsl + t * 16 * K1C + icc * 32);
            acc[t][0] = __builtin_amdgcn_mfma_f32_16x16x32_bf16(af, bf0, acc[t][0], 0, 0, 0);
            acc[t][1] = __builtin_amdgcn_mfma_f32_16x16x32_bf16(af, bf1, acc[t][1], 0, 0, 0);
        }
    }

    // epilogue: C layout col(px)=l16, row(oc_local)=q*4+r ; store NHWC bf16
    short* ob = out1b + ((size_t)(n * PIX1) + px0) * OCN + ochalf * 64 + q * 4;
#pragma unroll
    for (int t = 0; t < 4; t++) {
#pragma unroll
        for (int g = 0; g < 2; g++) {
            f32x4 a = acc[t][g];
            uint2 u;
            u.x = pack2bf(a[0], a[1]);
            u.y = pack2bf(a[2], a[3]);
            *(uint2*)(ob + (size_t)g * 16 * OCN + t * 16) = u;
        }
    }

    // fused BN1 stats: DPP 16-lane rowsum (VALU only) -> LDS -> block pass
#pragma unroll
    for (int t = 0; t < 4; t++) {
#pragma unroll
        for (int r = 0; r < 4; r++) {
            float a0 = acc[t][0][r], a1 = acc[t][1][r];
            float s = rowsum16(a0 + a1);
            float z = rowsum16(fmaf(a0, a0, a1 * a1));
            if (l16 == 0) {
                int ocl = t * 16 + q * 4 + r;     // 0..63
                sred[wave][ocl][0] = s;
                sred[wave][ocl][1] = z;
            }
        }
    }
    __syncthreads();
    if (tid < 64) {
        float s = sred[0][tid][0] + sred[1][tid][0] + sred[2][tid][0] + sred[3][tid][0];
        float z = sred[0][tid][1] + sred[1][tid][1] + sred[2][tid][1] + sred[3][tid][1];
        int oc = ochalf * 64 + tid;
        atomicAdd(&sum1x[n * OCN + oc], s);
        atomicAdd(&sq1x[n * OCN + oc], z);
    }
}

// ---------------------------------------------------------------------------
// Finalize BN params from per-n partial sums: 32x128 -> scale/shift.
__global__ void k_fin2(const float* __restrict__ sumx, const float* __restrict__ sqx,
                       const float* __restrict__ gamma, const float* __restrict__ beta,
                       float invN, float* __restrict__ scale, float* __restrict__ shift) {
    int c = threadIdx.x;
    if (c >= OCN) return;
    float s = 0.f, q = 0.f;
    for (int n = 0; n < BN_; n++) { s += sumx[n * OCN + c]; q += sqx[n * OCN + c]; }
    float m = s * invN;
    float v = q * invN - m * m;
    float sc = gamma[c] * rsqrtf(v + 1e-5f);
    scale[c] = sc;
    shift[c] = beta[c] - m * sc;
}

// ---------------------------------------------------------------------------
// BN1 affine + 3x3/2 maxpool + ReLU: NHWC bf16 (112x112) -> padded NHWC bf16
// (58x58). r5-proven: uint2-vectorized — 32 threads/px, 4 channels/thread,
// 8 px per block.
__global__ __launch_bounds__(256) void k_bnpool(const uint2* __restrict__ out1b,
                                                const float* __restrict__ scale,
                                                const float* __restrict__ shift,
                                                uint2* __restrict__ h2p) {
    int tid = threadIdx.x;
    int c4 = tid & 31, po = tid >> 5;
    int pp = blockIdx.x * 8 + po;
    int n = blockIdx.y;
    int py = pp / POOLSZ, px = pp % POOLSZ;
    const uint2* base = out1b + (size_t)n * PIX1 * 32;
    int c0 = c4 * 4;
    float4 sc = *(const float4*)(scale + c0);
    float4 sh = *(const float4*)(shift + c0);
    float m0 = -1e30f, m1 = -1e30f, m2 = -1e30f, m3 = -1e30f;
#pragma unroll
    for (int dy = 0; dy < 3; dy++) {
        int y = 2 * py - 1 + dy;
        if ((unsigned)y >= (unsigned)OUTSZ) continue;
#pragma unroll
        for (int dx = 0; dx < 3; dx++) {
            int x = 2 * px - 1 + dx;
            if ((unsigned)x >= (unsigned)OUTSZ) continue;
            uint2 u = base[(size_t)(y * OUTSZ + x) * 32 + c4];
            m0 = fmaxf(m0, fmaf(sc.x, __uint_as_float(u.x << 16), sh.x));
            m1 = fmaxf(m1, fmaf(sc.y, __uint_as_float(u.x & 0xffff0000u), sh.y));
            m2 = fmaxf(m2, fmaf(sc.z, __uint_as_float(u.y << 16), sh.z));
            m3 = fmaxf(m3, fmaf(sc.w, __uint_as_float(u.y & 0xffff0000u), sh.w));
        }
    }
    uint2 o;
    o.x = pack2bf(fmaxf(m0, 0.f), fmaxf(m1, 0.f));
    o.y = pack2bf(fmaxf(m2, 0.f), fmaxf(m3, 0.f));
    h2p[(size_t)n * (HSTRIDE / 4) + ((py + 1) * HP + (px + 1)) * 32 + c4] = o;
}

// ---------------------------------------------------------------------------
// conv2 (r1-proven, untouched): implicit GEMM, m97 structure. M=128 oc,
// N-tile=112 px (2 rows), BK=64 (18 K-steps). 4 waves, each 32 oc x 112 px.
// A (16 KB) + B (14 KB) single-buffer LDS via global_load_lds w=16; 2
// barriers/step; 4 blocks/CU. NHWC epilogue; DPP stats.
__global__ __launch_bounds__(256, 4) void k_conv2g(const short* __restrict__ h2p,
                                                   const short* __restrict__ w2b,
                                                   short* __restrict__ out2b,
                                                   float* __restrict__ sum2x,
                                                   float* __restrict__ sq2x) {
    __shared__ short LDSb[15360];          // A: [0,8192) shorts; B: [8192,15360)
    int tid = threadIdx.x;
    int wave = tid >> 6, lane = tid & 63;
    int q = lane >> 4, l16 = lane & 15;
    int id = blockIdx.x;                   // 0..895, XCD-major
    int xcd = id & 7, seq = id >> 3;       // seq 0..111
    int n = xcd + 8 * (seq / 28);
    int rb = seq % 28;
    int y0 = rb * 2;                       // output rows y0, y0+1
    const short* hb = h2p + (size_t)n * HSTRIDE;

    // B staging source offsets (elems, step-delta excluded)
    int bofs[4];
#pragma unroll
    for (int i = 0; i < 4; i++) {
        int ck = tid + i * 256;
        if (ck > 895) ck = 895;            // i==3, tid>=128: lanes inactive
        int px = ck >> 3, sl = ck & 7;
        int r = px >= 56;
        int xc = px - (r ? 56 : 0);
        bofs[i] = ((y0 + r) * 58 + xc) * 128 + ((sl ^ (px & 7)) * 8);
    }

    f32x4 acc[2][7];
#pragma unroll
    for (int t16 = 0; t16 < 2; t16++)
#pragma unroll
        for (int g = 0; g < 7; g++) acc[t16][g] = (f32x4){0, 0, 0, 0};

    const short* Az = LDSb;
    const short* Bz = LDSb + 8192;
    int arow0 = (wave * 32 + l16) * 64;
    int arow1 = arow0 + 16 * 64;

    for (int t = 0; t < 18; t++) {
        __syncthreads();                   // previous compute done in all waves
        // ---- stage A (4x16B/thread, linear) + B (3.5x16B/thread, pre-swz src)
        const short* wt = w2b + t * 8192;
#pragma unroll
        for (int i = 0; i < 4; i++)
            gload16(wt + (tid + i * 256) * 8, &LDSb[(tid + i * 256) * 8]);
        int s = t >> 1, ich = t & 1;
        int dy = s / 3, dx = s - dy * 3;
        int doff = (dy * 58 + dx) * 128 + ich * 64;
#pragma unroll
        for (int i = 0; i < 3; i++)
            gload16(hb + bofs[i] + doff, &LDSb[8192 + (tid + i * 256) * 8]);
        if (tid < 128)
            gload16(hb + bofs[3] + doff, &LDSb[8192 + (tid + 768) * 8]);
        asm volatile("s_waitcnt vmcnt(0)" ::: "memory");
        __syncthreads();
        // ---- compute: 2 k-sub x (2 A-frag reads + 7 B-frag reads + 14 MFMA)
#pragma unroll
        for (int icc2 = 0; icc2 < 2; icc2++) {
            int so = ((icc2 * 4 + q) ^ (l16 & 7)) * 8;
            bf16x8 af0 = *(const bf16x8*)(Az + arow0 + so);
            bf16x8 af1 = *(const bf16x8*)(Az + arow1 + so);
            bf16x8 bf[7];
#pragma unroll
            for (int g = 0; g < 7; g++)
                bf[g] = *(const bf16x8*)(Bz + (g * 16 + l16) * 64 + so);
#pragma unroll
            for (int g = 0; g < 7; g++) {
                acc[0][g] = __builtin_amdgcn_mfma_f32_16x16x32_bf16(af0, bf[g], acc[0][g], 0, 0, 0);
                acc[1][g] = __builtin_amdgcn_mfma_f32_16x16x32_bf16(af1, bf[g], acc[1][g], 0, 0, 0);
            }
        }
    }

    // ---- epilogue: C col(px)=l16, row(oc)=q*4+r ; store NHWC bf16 ----
    short* ob = out2b + ((size_t)n * PIX2 + y0 * 56) * OCN + wave * 32 + q * 4;
#pragma unroll
    for (int t16 = 0; t16 < 2; t16++) {
#pragma unroll
        for (int g = 0; g < 7; g++) {
            f32x4 a = acc[t16][g];
            uint2 u;
            u.x = pack2bf(a[0], a[1]);
            u.y = pack2bf(a[2], a[3]);
            *(uint2*)(ob + (size_t)(g * 16 + l16) * OCN + t16 * 16) = u;
        }
    }

    // ---- fused BN2 stats: DPP rowsum; waves own distinct oc -> atomics ----
#pragma unroll
    for (int t16 = 0; t16 < 2; t16++) {
#pragma unroll
        for (int r = 0; r < 4; r++) {
            float sv = 0.f, zv = 0.f;
#pragma unroll
            for (int g = 0; g < 7; g++) {
                float v = acc[t16][g][r];
                sv += v;
                zv = fmaf(v, v, zv);
            }
            sv = rowsum16(sv);
            zv = rowsum16(zv);
            if (l16 == 0) {
                int oc = wave * 32 + t16 * 16 + q * 4 + r;
                atomicAdd(&sum2x[n * OCN + oc], sv);
                atomicAdd(&sq2x[n * OCN + oc], zv);
            }
        }
    }
}

// ---------------------------------------------------------------------------
// BN2 affine + ReLU: NHWC bf16 out2b -> NCHW fp32 d_out.
// Thread = 4 px x 8 c (x4 c-groups): register-local 4x8 transpose, no LDS.
__global__ __launch_bounds__(256) void k_bnrelu(const short* __restrict__ in2,
                                                float* __restrict__ y,
                                                const float* __restrict__ scale,
                                                const float* __restrict__ shift) {
    int tid = threadIdx.x;
    int w = tid >> 6, l = tid & 63;
    int pxg = blockIdx.x * 256 + w * 64 + (l & 15) * 4;  // wave spans 64 px (never crosses n)
    int n = pxg / PIX2;
    int px = pxg - n * PIX2;
    const short* src = in2 + (size_t)pxg * OCN + (l >> 4) * 8;
    float* dst = y + (size_t)n * (OCN * PIX2) + px;
#pragma unroll
    for (int jc = 0; jc < 4; jc++) {
        int c0 = (l >> 4) * 8 + jc * 32;
        bf16x8 v0 = ldb8(src + jc * 32);
        bf16x8 v1 = ldb8(src + OCN + jc * 32);
        bf16x8 v2 = ldb8(src + 2 * OCN + jc * 32);
        bf16x8 v3 = ldb8(src + 3 * OCN + jc * 32);
#pragma unroll
        for (int j = 0; j < 8; j++) {
            float sc = scale[c0 + j], sh = shift[c0 + j];
            float4 o;
            o.x = fmaxf(fmaf(sc, bf2f(v0[j]), sh), 0.f);
            o.y = fmaxf(fmaf(sc, bf2f(v1[j]), sh), 0.f);
            o.z = fmaxf(fmaf(sc, bf2f(v2[j]), sh), 0.f);
            o.w = fmaxf(fmaf(sc, bf2f(v3[j]), sh), 0.f);
            *(float4*)(dst + (size_t)(c0 + j) * PIX2) = o;
        }
    }
}

// ---------------------------------------------------------------------------
extern "C" void kernel_launch(void* const* d_in, const int* in_sizes, int n_in,
                              void* d_out, int out_size, void* d_ws, size_t ws_size,
                              hipStream_t stream) {
    const float* inp = (const float*)d_in[0];
    const float* w1  = (const float*)d_in[1];
    const float* g1  = (const float*)d_in[2];
    const float* b1  = (const float*)d_in[3];
    const float* w2  = (const float*)d_in[4];
    const float* g2  = (const float*)d_in[5];
    const float* b2  = (const float*)d_in[6];
    float* out = (float*)d_out;

    char* ws = (char*)d_ws;
    int2*  map   = (int2*)ws;                         // 100,352 B
    float* stats = (float*)(ws + 102400);             // 65,536 B zeroed in k_setup
    short* w2b   = (short*)(ws + 176128);             // 294,912 B -> 471,040
    short* w1b   = (short*)(ws + 471040);             // 49,152 B  -> 520,192
    short* padA  = (short*)(ws + 520192);             // 10,736,640 B -> 11,256,832
    short* padB  = (short*)(ws + 11256832ULL);        // 10,736,640 B -> 21,993,472
    short* h2p   = (short*)(ws + 21993472ULL);        // 27,557,888 B -> 49,551,360
    short* out1b = (short*)(ws + 49551360ULL);        // 102,760,448 B -> 152,311,808
    short* out2b = (short*)(ws + 152311808ULL);       // 25,690,112 B -> 178,001,920 (NHWC)

    float* sum1x = stats;                // 32*128
    float* sq1x  = stats + 4096;
    float* sum2x = stats + 8192;
    float* sq2x  = stats + 12288;
    float* SC1 = stats + 16384, *SH1 = stats + 16512;
    float* SC2 = stats + 16640, *SH2 = stats + 16768;

    k_setup <<<dim3(2609 + PH * 96), 256, 0, stream>>>(w1, w1b, w2, w2b, map, stats,
                                                       (unsigned*)h2p, inp, padA, padB);
    k_conv1m<<<dim3(6272), 256, 0, stream>>>(padA, padB, w1b, map, out1b, sum1x, sq1x);
    k_fin2  <<<1, 128, 0, stream>>>(sum1x, sq1x, g1, b1, 1.f / (BN_ * PIX1), SC1, SH1);
    k_bnpool<<<dim3(PIX2 / 8, BN_), 256, 0, stream>>>((const uint2*)out1b, SC1, SH1, (uint2*)h2p);
    k_conv2g<<<dim3(896), 256, 0, stream>>>(h2p, w2b, out2b, sum2x, sq2x);
    k_fin2  <<<1, 128, 0, stream>>>(sum2x, sq2x, g2, b2, 1.f / (BN_ * PIX2), SC2, SH2);
    k_bnrelu<<<dim3(392), 256, 0, stream>>>(out2b, out, SC2, SH2);
}

// Round 8
// 232.339 us; speedup vs baseline: 1.2257x; 1.2257x over previous
//
#include <hip/hip_runtime.h>
#include <hip/hip_bf16.h>
#include <cstdint>

// ---------------------------------------------------------------------------
#define IMGSZ 224
#define OUTSZ 112
#define POOLSZ 56
#define OCN 128
#define BN_ 32
#define PIX1 (OUTSZ*OUTSZ)     // 12544
#define PIX2 (POOLSZ*POOLSZ)   // 3136
#define HP 58                  // padded pooled dim (56 + 2)
#define HSTRIDE (HP*HP*OCN)    // elems per n in h2p
#define PW 240                 // padded input row stride (x in [-3,236))
#define PH 233                 // padded input rows (y in [-3,230))
#define PPL (PH*PW)            // 55920 elems per padded plane
#define K1C 192                // conv1 K: 24 groups of 8 = (ic*7+ky)*8+kx layout

typedef float f32x4 __attribute__((ext_vector_type(4)));
typedef short bf16x8 __attribute__((ext_vector_type(8)));
struct alignas(4) u4a { unsigned x, y, z, w; };   // 4B-aligned 16B load

__device__ inline short f2bf(float v) {
    __hip_bfloat16 h = __float2bfloat16(v);
    return *(short*)&h;
}
__device__ inline unsigned pack2bf(float a, float b) {
    return (unsigned short)f2bf(a) | ((unsigned)(unsigned short)f2bf(b) << 16);
}
__device__ inline float bf2f(short s) {
    return __uint_as_float(((unsigned)(unsigned short)s) << 16);
}
__device__ inline bf16x8 ldb8(const short* p) {   // 16B load, 4B-aligned
    u4a t = *(const u4a*)p;
    union { u4a u; bf16x8 v; } c; c.u = t; return c.v;
}
__device__ inline void gload16(const short* g, short* l) {   // async global->LDS, 16B/lane
    __builtin_amdgcn_global_load_lds((const __attribute__((address_space(1))) void*)g,
                                     (__attribute__((address_space(3))) void*)l, 16, 0, 0);
}

// DPP 16-lane sum: quad_perm xor1, xor2, row_half_mirror, row_mirror.
// Pure VALU — replaces the 4-step ds_swizzle butterfly (DS pipe relief).
template<int CTRL>
__device__ inline float dppf(float v) {
    return __int_as_float(__builtin_amdgcn_update_dpp(0, __float_as_int(v), CTRL, 0xF, 0xF, true));
}
__device__ inline float rowsum16(float v) {
    v += dppf<0xB1>(v);    // quad_perm [1,0,3,2]  (xor 1)
    v += dppf<0x4E>(v);    // quad_perm [2,3,0,1]  (xor 2)
    v += dppf<0x141>(v);   // row_half_mirror      (8-group sum)
    v += dppf<0x140>(v);   // row_mirror           (16-group sum)
    return v;              // all 16 lanes of each row hold the 16-sum
}

// ---------------------------------------------------------------------------
// Fused setup + pad: [0,49) map ; [49,145) wpack1 ; [145,721) wconv2 pack ;
// [721,785) stats zero ; [785,2609) h2p halo zero ; [2609,24977) input pad.
// wconv2 pack: w2b holds 18 K-step tiles (t = s*2 + ic_half), each the EXACT
// 16 KB LDS image: [oc 128][8 chunks of 16B], chunk slot = (ic6>>3) ^ (oc&7).
// pad: zero-haloed bf16 input, TWO copies: padA[x]=img[x-3], padB[x]=img[x-2].
__global__ __launch_bounds__(256) void k_setup(const float* __restrict__ w1,
                                               short* __restrict__ w1b,
                                               const float* __restrict__ w2,
                                               short* __restrict__ w2b,
                                               int2* __restrict__ map,
                                               float* __restrict__ stats,
                                               unsigned* __restrict__ h2p,
                                               const float* __restrict__ inp,
                                               short* __restrict__ padA,
                                               short* __restrict__ padB) {
    int blk = blockIdx.x;
    int tid = threadIdx.x;
    if (blk >= 2609) {                    // pad section: 22368 blocks
        int idx = blk - 2609;
        int pl = idx / PH, y = idx - (idx / PH) * PH;
        int x = tid;
        if (x >= PW) return;
        int iy = y - 3;
        bool yok = (unsigned)iy < 224u;
        const float* src = inp + (size_t)pl * 50176 + iy * 224;
        float vA = (yok && (unsigned)(x - 3) < 224u) ? src[x - 3] : 0.f;
        float vB = (yok && (unsigned)(x - 2) < 224u) ? src[x - 2] : 0.f;
        size_t o = (size_t)pl * PPL + y * PW + x;
        padA[o] = f2bf(vA);
        padB[o] = f2bf(vB);
        return;
    }
    if (blk < 49) {
        int p = blk * 256 + tid;
        int oy = p / OUTSZ, ox = p % OUTSZ;
        int e = min(min(oy, ox), min(111 - oy, 111 - ox));
        int s = e >> 3;
        int a = 16 * s, b = a + 16, c = 224 - b, d = 224 - a;
        int ao = a >> 1, bo = b >> 1, co = c >> 1, dd = d >> 1;
        int ti, li, bi, ri;
        if      (oy >= ao && oy < bo && ox >= ao && ox < co) { ti=a; li=a; bi=b; ri=c; }
        else if (oy >= bo && oy < dd && ox >= ao && ox < bo) { ti=b; li=a; bi=d; ri=b; }
        else if (oy >= co && oy < dd && ox >= bo && ox < dd) { ti=c; li=b; bi=d; ri=d; }
        else                                                 { ti=a; li=c; bi=c; ri=d; }
        float scale = (float)(2.0 - (double)s * 0.16666666666666666);
        int tip = (int)((float)(ti + 6) / scale) - 3;
        int lip = (int)((float)(li + 6) / scale) - 3;
        int bip = (int)((float)(bi + 6) / scale) + 3;
        int rip = (int)((float)(ri + 6) / scale) + 3;
        int fh = (bip - tip - 7) / 2 + 1;
        int fw = (rip - lip - 7) / 2 + 1;
        int to = ti >> 1, lo = li >> 1, bo2 = bi >> 1, ro = ri >> 1;
        int i = oy - to, j = ox - lo;
        int pp = (i * fh) / (bo2 - to);
        int qq = (j * fw) / (ro - lo);
        map[p] = make_int2(tip + 2 * pp, lip + 2 * qq);
    } else if (blk < 145) {
        int idx = (blk - 49) * 256 + tid;
        int oc = idx / K1C, k = idx % K1C;
        int g8 = k >> 3, e2 = k & 7;
        float v = 0.f;
        if (g8 < 21 && e2 < 7) {
            int ic = g8 / 7, ky = g8 - ic * 7;
            v = w1[((oc * 3 + ic) * 7 + ky) * 7 + e2];
        }
        w1b[idx] = f2bf(v);
    } else if (blk < 721) {
        int idx = (blk - 145) * 256 + tid;      // input element of w2 (OIHW flat)
        int oc = idx / 1152;
        int rem = idx - oc * 1152;
        int ic = rem / 9;
        int s  = rem - ic * 9;
        int t  = s * 2 + (ic >> 6);             // K-step
        int ic6 = ic & 63;
        int slot = (ic6 >> 3) ^ (oc & 7);       // XOR-swizzled 16B chunk slot
        w2b[t * 8192 + oc * 64 + slot * 8 + (ic6 & 7)] = f2bf(w2[idx]);
    } else if (blk < 785) {
        stats[(blk - 721) * 256 + tid] = 0.f;
    } else {
        int idx = blk - 785;                  // 0..1823
        int bx = idx % 57, n = idx / 57;
        int c2 = tid & 63, po = tid >> 6;
        int pp = bx * 4 + po;                 // 0..227
        int y, x;
        if      (pp < 58)  { y = 0;  x = pp; }
        else if (pp < 116) { y = 57; x = pp - 58; }
        else if (pp < 172) { y = pp - 116 + 1; x = 0; }
        else               { y = pp - 172 + 1; x = 57; }
        h2p[(size_t)n * (HSTRIDE / 2) + (y * HP + x) * 64 + c2] = 0u;
    }
}

// ---------------------------------------------------------------------------
// conv1 (r4/r5-proven, restored verbatim): wave = 64 oc x 32 px; block = 4
// waves x 32 px = 128 px on one 64-oc A-slice. A staged ONCE in LDS (32 KB,
// 16B-chunk XOR swizzle — measured-best layout); B = 12 up-front global 16B
// gathers. XCD n-chunked grid (pad gather L2-resident/XCD); 4 blocks/CU (the
// L2 write-combining sweet spot, r2/r5); DPP stats.
// r6 lesson: do NOT replace LDS staging with per-MFMA global loads — LDS is
// the latency decoupler (r6: 103 µs, VGPR 44, all pipes idle).
__global__ __launch_bounds__(256, 4) void k_conv1m(const short* __restrict__ padA,
                                                   const short* __restrict__ padB,
                                                   const short* __restrict__ w1b,
                                                   const int2* __restrict__ map,
                                                   short* __restrict__ out1b,
                                                   float* __restrict__ sum1x,
                                                   float* __restrict__ sq1x) {
    __shared__ short As[64 * 256];     // 32 KB: row r, 16B-chunk c at pos c^(r&15)
    __shared__ float sred[4][64][2];   // 2 KB
    int tid = threadIdx.x;
    int wave = tid >> 6, lane = tid & 63;
    int q = lane >> 4, l16 = lane & 15;
    // XCD-chunked id remap: 6272 = 8 XCD x 784; 784 = 4 images x 196 blocks.
    int id = blockIdx.x;
    int swz = (id & 7) * 784 + (id >> 3);
    int n = swz / 196;
    int x196 = swz - n * 196;
    int ochalf = x196 & 1;
    int pxblk = x196 >> 1;                            // 0..97
    int px0 = pxblk * 128 + wave * 32 + l16;
    int px1 = px0 + 16;
    int2 m0 = map[px0];
    int2 m1 = map[px1];
    size_t bn = (size_t)n * 3 * PPL;
    const short* r0 = ((m0.y & 1) ? padB + (m0.y - 1) : padA + m0.y) + bn + m0.x * PW;
    const short* r1 = ((m1.y & 1) ? padB + (m1.y - 1) : padA + m1.y) + bn + m1.x * PW;

    // Stage A: 64 rows x 24 chunks of 16B = 1536 chunks; 6 per thread.
    const short* wsl = w1b + ochalf * 64 * K1C;
#pragma unroll
    for (int i = 0; i < 6; i++) {
        int chunk = tid + i * 256;
        int r = chunk / 24, c = chunk - r * 24;
        u4a v = *(const u4a*)(wsl + r * K1C + c * 8);
        *(u4a*)(As + r * 256 + ((c ^ (r & 15)) * 8)) = v;
    }

    // B loads (up-front, in-order consumption)
    bf16x8 ld[12];
#pragma unroll
    for (int icc = 0; icc < 6; icc++) {
        int g8 = (icc == 5) ? 20 : (icc * 4 + q);
        int ic = (g8 >= 7) + (g8 >= 14);
        int ky = g8 - ic * 7;
        int off = ic * PPL + ky * PW;
        ld[icc * 2]     = ldb8(r0 + off);
        ld[icc * 2 + 1] = ldb8(r1 + off);
    }

    f32x4 acc[4][2];
#pragma unroll
    for (int t = 0; t < 4; t++) { acc[t][0] = (f32x4){0,0,0,0}; acc[t][1] = (f32x4){0,0,0,0}; }

    __syncthreads();

    const short* Abase = As + l16 * 256;   // + t*16*256 + swizzled chunk
#pragma unroll
    for (int icc = 0; icc < 6; icc++) {
        bf16x8 bf0 = ld[icc * 2];
        bf16x8 bf1 = ld[icc * 2 + 1];
        int pos = ((icc * 4 + q) ^ l16) * 8;
#pragma unroll
        for (int t = 0; t < 4; t++) {
            bf16x8 af = *(const bf16x8*)(Abase + t * 16 * 256 + pos);
            acc[t][0] = __builtin_amdgcn_mfma_f32_16x16x32_bf16(af, bf0, acc[t][0], 0, 0, 0);
            acc[t][1] = __builtin_amdgcn_mfma_f32_16x16x32_bf16(af, bf1, acc[t][1], 0, 0, 0);
        }
    }

    // epilogue: C layout col(px)=l16, row(oc_local)=q*4+r ; store NHWC bf16
    short* ob = out1b + ((size_t)(n * PIX1) + px0) * OCN + ochalf * 64 + q * 4;
#pragma unroll
    for (int t = 0; t < 4; t++) {
#pragma unroll
        for (int g = 0; g < 2; g++) {
            f32x4 a = acc[t][g];
            uint2 u;
            u.x = pack2bf(a[0], a[1]);
            u.y = pack2bf(a[2], a[3]);
            *(uint2*)(ob + (size_t)g * 16 * OCN + t * 16) = u;
        }
    }

    // fused BN1 stats: DPP 16-lane rowsum (VALU only) -> LDS -> block pass
#pragma unroll
    for (int t = 0; t < 4; t++) {
#pragma unroll
        for (int r = 0; r < 4; r++) {
            float a0 = acc[t][0][r], a1 = acc[t][1][r];
            float s = rowsum16(a0 + a1);
            float z = rowsum16(fmaf(a0, a0, a1 * a1));
            if (l16 == 0) {
                int ocl = t * 16 + q * 4 + r;     // 0..63
                sred[wave][ocl][0] = s;
                sred[wave][ocl][1] = z;
            }
        }
    }
    __syncthreads();
    if (tid < 64) {
        float s = sred[0][tid][0] + sred[1][tid][0] + sred[2][tid][0] + sred[3][tid][0];
        float z = sred[0][tid][1] + sred[1][tid][1] + sred[2][tid][1] + sred[3][tid][1];
        int oc = ochalf * 64 + tid;
        atomicAdd(&sum1x[n * OCN + oc], s);
        atomicAdd(&sq1x[n * OCN + oc], z);
    }
}

// ---------------------------------------------------------------------------
// Finalize BN params from per-n partial sums: 32x128 -> scale/shift.
__global__ void k_fin2(const float* __restrict__ sumx, const float* __restrict__ sqx,
                       const float* __restrict__ gamma, const float* __restrict__ beta,
                       float invN, float* __restrict__ scale, float* __restrict__ shift) {
    int c = threadIdx.x;
    if (c >= OCN) return;
    float s = 0.f, q = 0.f;
    for (int n = 0; n < BN_; n++) { s += sumx[n * OCN + c]; q += sqx[n * OCN + c]; }
    float m = s * invN;
    float v = q * invN - m * m;
    float sc = gamma[c] * rsqrtf(v + 1e-5f);
    scale[c] = sc;
    shift[c] = beta[c] - m * sc;
}

// ---------------------------------------------------------------------------
// BN1 affine + 3x3/2 maxpool + ReLU: NHWC bf16 (112x112) -> padded NHWC bf16
// (58x58). r5-proven: uint2-vectorized — 32 threads/px, 4 channels/thread,
// 8 px per block.
__global__ __launch_bounds__(256) void k_bnpool(const uint2* __restrict__ out1b,
                                                const float* __restrict__ scale,
                                                const float* __restrict__ shift,
                                                uint2* __restrict__ h2p) {
    int tid = threadIdx.x;
    int c4 = tid & 31, po = tid >> 5;
    int pp = blockIdx.x * 8 + po;
    int n = blockIdx.y;
    int py = pp / POOLSZ, px = pp % POOLSZ;
    const uint2* base = out1b + (size_t)n * PIX1 * 32;
    int c0 = c4 * 4;
    float4 sc = *(const float4*)(scale + c0);
    float4 sh = *(const float4*)(shift + c0);
    float m0 = -1e30f, m1 = -1e30f, m2 = -1e30f, m3 = -1e30f;
#pragma unroll
    for (int dy = 0; dy < 3; dy++) {
        int y = 2 * py - 1 + dy;
        if ((unsigned)y >= (unsigned)OUTSZ) continue;
#pragma unroll
        for (int dx = 0; dx < 3; dx++) {
            int x = 2 * px - 1 + dx;
            if ((unsigned)x >= (unsigned)OUTSZ) continue;
            uint2 u = base[(size_t)(y * OUTSZ + x) * 32 + c4];
            m0 = fmaxf(m0, fmaf(sc.x, __uint_as_float(u.x << 16), sh.x));
            m1 = fmaxf(m1, fmaf(sc.y, __uint_as_float(u.x & 0xffff0000u), sh.y));
            m2 = fmaxf(m2, fmaf(sc.z, __uint_as_float(u.y << 16), sh.z));
            m3 = fmaxf(m3, fmaf(sc.w, __uint_as_float(u.y & 0xffff0000u), sh.w));
        }
    }
    uint2 o;
    o.x = pack2bf(fmaxf(m0, 0.f), fmaxf(m1, 0.f));
    o.y = pack2bf(fmaxf(m2, 0.f), fmaxf(m3, 0.f));
    h2p[(size_t)n * (HSTRIDE / 4) + ((py + 1) * HP + (px + 1)) * 32 + c4] = o;
}

// ---------------------------------------------------------------------------
// conv2 (r1-proven, untouched): implicit GEMM, m97 structure. M=128 oc,
// N-tile=112 px (2 rows), BK=64 (18 K-steps). 4 waves, each 32 oc x 112 px.
// A (16 KB) + B (14 KB) single-buffer LDS via global_load_lds w=16; 2
// barriers/step; 4 blocks/CU. NHWC epilogue; DPP stats.
__global__ __launch_bounds__(256, 4) void k_conv2g(const short* __restrict__ h2p,
                                                   const short* __restrict__ w2b,
                                                   short* __restrict__ out2b,
                                                   float* __restrict__ sum2x,
                                                   float* __restrict__ sq2x) {
    __shared__ short LDSb[15360];          // A: [0,8192) shorts; B: [8192,15360)
    int tid = threadIdx.x;
    int wave = tid >> 6, lane = tid & 63;
    int q = lane >> 4, l16 = lane & 15;
    int id = blockIdx.x;                   // 0..895, XCD-major
    int xcd = id & 7, seq = id >> 3;       // seq 0..111
    int n = xcd + 8 * (seq / 28);
    int rb = seq % 28;
    int y0 = rb * 2;                       // output rows y0, y0+1
    const short* hb = h2p + (size_t)n * HSTRIDE;

    // B staging source offsets (elems, step-delta excluded)
    int bofs[4];
#pragma unroll
    for (int i = 0; i < 4; i++) {
        int ck = tid + i * 256;
        if (ck > 895) ck = 895;            // i==3, tid>=128: lanes inactive
        int px = ck >> 3, sl = ck & 7;
        int r = px >= 56;
        int xc = px - (r ? 56 : 0);
        bofs[i] = ((y0 + r) * 58 + xc) * 128 + ((sl ^ (px & 7)) * 8);
    }

    f32x4 acc[2][7];
#pragma unroll
    for (int t16 = 0; t16 < 2; t16++)
#pragma unroll
        for (int g = 0; g < 7; g++) acc[t16][g] = (f32x4){0, 0, 0, 0};

    const short* Az = LDSb;
    const short* Bz = LDSb + 8192;
    int arow0 = (wave * 32 + l16) * 64;
    int arow1 = arow0 + 16 * 64;

    for (int t = 0; t < 18; t++) {
        __syncthreads();                   // previous compute done in all waves
        // ---- stage A (4x16B/thread, linear) + B (3.5x16B/thread, pre-swz src)
        const short* wt = w2b + t * 8192;
#pragma unroll
        for (int i = 0; i < 4; i++)
            gload16(wt + (tid + i * 256) * 8, &LDSb[(tid + i * 256) * 8]);
        int s = t >> 1, ich = t & 1;
        int dy = s / 3, dx = s - dy * 3;
        int doff = (dy * 58 + dx) * 128 + ich * 64;
#pragma unroll
        for (int i = 0; i < 3; i++)
            gload16(hb + bofs[i] + doff, &LDSb[8192 + (tid + i * 256) * 8]);
        if (tid < 128)
            gload16(hb + bofs[3] + doff, &LDSb[8192 + (tid + 768) * 8]);
        asm volatile("s_waitcnt vmcnt(0)" ::: "memory");
        __syncthreads();
        // ---- compute: 2 k-sub x (2 A-frag reads + 7 B-frag reads + 14 MFMA)
#pragma unroll
        for (int icc2 = 0; icc2 < 2; icc2++) {
            int so = ((icc2 * 4 + q) ^ (l16 & 7)) * 8;
            bf16x8 af0 = *(const bf16x8*)(Az + arow0 + so);
            bf16x8 af1 = *(const bf16x8*)(Az + arow1 + so);
            bf16x8 bf[7];
#pragma unroll
            for (int g = 0; g < 7; g++)
                bf[g] = *(const bf16x8*)(Bz + (g * 16 + l16) * 64 + so);
#pragma unroll
            for (int g = 0; g < 7; g++) {
                acc[0][g] = __builtin_amdgcn_mfma_f32_16x16x32_bf16(af0, bf[g], acc[0][g], 0, 0, 0);
                acc[1][g] = __builtin_amdgcn_mfma_f32_16x16x32_bf16(af1, bf[g], acc[1][g], 0, 0, 0);
            }
        }
    }

    // ---- epilogue: C col(px)=l16, row(oc)=q*4+r ; store NHWC bf16 ----
    short* ob = out2b + ((size_t)n * PIX2 + y0 * 56) * OCN + wave * 32 + q * 4;
#pragma unroll
    for (int t16 = 0; t16 < 2; t16++) {
#pragma unroll
        for (int g = 0; g < 7; g++) {
            f32x4 a = acc[t16][g];
            uint2 u;
            u.x = pack2bf(a[0], a[1]);
            u.y = pack2bf(a[2], a[3]);
            *(uint2*)(ob + (size_t)(g * 16 + l16) * OCN + t16 * 16) = u;
        }
    }

    // ---- fused BN2 stats: DPP rowsum; waves own distinct oc -> atomics ----
#pragma unroll
    for (int t16 = 0; t16 < 2; t16++) {
#pragma unroll
        for (int r = 0; r < 4; r++) {
            float sv = 0.f, zv = 0.f;
#pragma unroll
            for (int g = 0; g < 7; g++) {
                float v = acc[t16][g][r];
                sv += v;
                zv = fmaf(v, v, zv);
            }
            sv = rowsum16(sv);
            zv = rowsum16(zv);
            if (l16 == 0) {
                int oc = wave * 32 + t16 * 16 + q * 4 + r;
                atomicAdd(&sum2x[n * OCN + oc], sv);
                atomicAdd(&sq2x[n * OCN + oc], zv);
            }
        }
    }
}

// ---------------------------------------------------------------------------
// BN2 affine + ReLU: NHWC bf16 out2b -> NCHW fp32 d_out.
// r7: jc channel-group split across gridDim.y = 4 (392 -> 1568 blocks; the
// 392-block version was occupancy-starved at ~1.5 blocks/CU for a 77 MB
// streaming kernel). Same per-iteration access pattern and total traffic.
__global__ __launch_bounds__(256) void k_bnrelu(const short* __restrict__ in2,
                                                float* __restrict__ y,
                                                const float* __restrict__ scale,
                                                const float* __restrict__ shift) {
    int tid = threadIdx.x;
    int w = tid >> 6, l = tid & 63;
    int jc = blockIdx.y;                                 // 0..3 channel group
    int pxg = blockIdx.x * 256 + w * 64 + (l & 15) * 4;  // wave spans 64 px (never crosses n)
    int n = pxg / PIX2;
    int px = pxg - n * PIX2;
    const short* src = in2 + (size_t)pxg * OCN + (l >> 4) * 8 + jc * 32;
    float* dst = y + (size_t)n * (OCN * PIX2) + px;
    int c0 = (l >> 4) * 8 + jc * 32;
    bf16x8 v0 = ldb8(src);
    bf16x8 v1 = ldb8(src + OCN);
    bf16x8 v2 = ldb8(src + 2 * OCN);
    bf16x8 v3 = ldb8(src + 3 * OCN);
#pragma unroll
    for (int j = 0; j < 8; j++) {
        float sc = scale[c0 + j], sh = shift[c0 + j];
        float4 o;
        o.x = fmaxf(fmaf(sc, bf2f(v0[j]), sh), 0.f);
        o.y = fmaxf(fmaf(sc, bf2f(v1[j]), sh), 0.f);
        o.z = fmaxf(fmaf(sc, bf2f(v2[j]), sh), 0.f);
        o.w = fmaxf(fmaf(sc, bf2f(v3[j]), sh), 0.f);
        *(float4*)(dst + (size_t)(c0 + j) * PIX2) = o;
    }
}

// ---------------------------------------------------------------------------
extern "C" void kernel_launch(void* const* d_in, const int* in_sizes, int n_in,
                              void* d_out, int out_size, void* d_ws, size_t ws_size,
                              hipStream_t stream) {
    const float* inp = (const float*)d_in[0];
    const float* w1  = (const float*)d_in[1];
    const float* g1  = (const float*)d_in[2];
    const float* b1  = (const float*)d_in[3];
    const float* w2  = (const float*)d_in[4];
    const float* g2  = (const float*)d_in[5];
    const float* b2  = (const float*)d_in[6];
    float* out = (float*)d_out;

    char* ws = (char*)d_ws;
    int2*  map   = (int2*)ws;                         // 100,352 B
    float* stats = (float*)(ws + 102400);             // 65,536 B zeroed in k_setup
    short* w2b   = (short*)(ws + 176128);             // 294,912 B -> 471,040
    short* w1b   = (short*)(ws + 471040);             // 49,152 B  -> 520,192
    short* padA  = (short*)(ws + 520192);             // 10,736,640 B -> 11,256,832
    short* padB  = (short*)(ws + 11256832ULL);        // 10,736,640 B -> 21,993,472
    short* h2p   = (short*)(ws + 21993472ULL);        // 27,557,888 B -> 49,551,360
    short* out1b = (short*)(ws + 49551360ULL);        // 102,760,448 B -> 152,311,808
    short* out2b = (short*)(ws + 152311808ULL);       // 25,690,112 B -> 178,001,920 (NHWC)

    float* sum1x = stats;                // 32*128
    float* sq1x  = stats + 4096;
    float* sum2x = stats + 8192;
    float* sq2x  = stats + 12288;
    float* SC1 = stats + 16384, *SH1 = stats + 16512;
    float* SC2 = stats + 16640, *SH2 = stats + 16768;

    k_setup <<<dim3(2609 + PH * 96), 256, 0, stream>>>(w1, w1b, w2, w2b, map, stats,
                                                       (unsigned*)h2p, inp, padA, padB);
    k_conv1m<<<dim3(6272), 256, 0, stream>>>(padA, padB, w1b, map, out1b, sum1x, sq1x);
    k_fin2  <<<1, 128, 0, stream>>>(sum1x, sq1x, g1, b1, 1.f / (BN_ * PIX1), SC1, SH1);
    k_bnpool<<<dim3(PIX2 / 8, BN_), 256, 0, stream>>>((const uint2*)out1b, SC1, SH1, (uint2*)h2p);
    k_conv2g<<<dim3(896), 256, 0, stream>>>(h2p, w2b, out2b, sum2x, sq2x);
    k_fin2  <<<1, 128, 0, stream>>>(sum2x, sq2x, g2, b2, 1.f / (BN_ * PIX2), SC2, SH2);
    k_bnrelu<<<dim3(392, 4), 256, 0, stream>>>(out2b, out, SC2, SH2);
}

// Round 9
// 226.677 us; speedup vs baseline: 1.2563x; 1.0250x over previous
//
#include <hip/hip_runtime.h>
#include <hip/hip_bf16.h>
#include <cstdint>

// ---------------------------------------------------------------------------
#define IMGSZ 224
#define OUTSZ 112
#define POOLSZ 56
#define OCN 128
#define BN_ 32
#define PIX1 (OUTSZ*OUTSZ)     // 12544
#define PIX2 (POOLSZ*POOLSZ)   // 3136
#define HP 58                  // padded pooled dim (56 + 2)
#define HSTRIDE (HP*HP*OCN)    // elems per n in h2p
#define PW 240                 // padded input row stride (x in [-3,236))
#define PH 233                 // padded input rows (y in [-3,230))
#define PPL (PH*PW)            // 55920 elems per padded plane
#define K1C 192                // conv1 K: 24 groups of 8 = (ic*7+ky)*8+kx layout

typedef float f32x4 __attribute__((ext_vector_type(4)));
typedef short bf16x8 __attribute__((ext_vector_type(8)));
struct alignas(4) u4a { unsigned x, y, z, w; };   // 4B-aligned 16B load

__device__ inline short f2bf(float v) {
    __hip_bfloat16 h = __float2bfloat16(v);
    return *(short*)&h;
}
__device__ inline unsigned pack2bf(float a, float b) {
    return (unsigned short)f2bf(a) | ((unsigned)(unsigned short)f2bf(b) << 16);
}
__device__ inline float bf2f(short s) {
    return __uint_as_float(((unsigned)(unsigned short)s) << 16);
}
__device__ inline bf16x8 ldb8(const short* p) {   // 16B load, 4B-aligned
    u4a t = *(const u4a*)p;
    union { u4a u; bf16x8 v; } c; c.u = t; return c.v;
}
__device__ inline void gload16(const short* g, short* l) {   // async global->LDS, 16B/lane
    __builtin_amdgcn_global_load_lds((const __attribute__((address_space(1))) void*)g,
                                     (__attribute__((address_space(3))) void*)l, 16, 0, 0);
}

// DPP 16-lane sum: quad_perm xor1, xor2, row_half_mirror, row_mirror.
// Pure VALU — replaces the 4-step ds_swizzle butterfly (DS pipe relief).
template<int CTRL>
__device__ inline float dppf(float v) {
    return __int_as_float(__builtin_amdgcn_update_dpp(0, __float_as_int(v), CTRL, 0xF, 0xF, true));
}
__device__ inline float rowsum16(float v) {
    v += dppf<0xB1>(v);    // quad_perm [1,0,3,2]  (xor 1)
    v += dppf<0x4E>(v);    // quad_perm [2,3,0,1]  (xor 2)
    v += dppf<0x141>(v);   // row_half_mirror      (8-group sum)
    v += dppf<0x140>(v);   // row_mirror           (16-group sum)
    return v;              // all 16 lanes of each row hold the 16-sum
}

// ---------------------------------------------------------------------------
// Fused setup + pad: [0,49) map ; [49,145) wpack1 ; [145,721) wconv2 pack ;
// [721,785) stats zero ; [785,2609) h2p halo zero ; [2609,8273) input pad.
// wconv2 pack: w2b holds 18 K-step tiles (t = s*2 + ic_half), each the EXACT
// 16 KB LDS image: [oc 128][8 chunks of 16B], chunk slot = (ic6>>3) ^ (oc&7).
// pad (r8: vectorized): 4 px/thread, 5 guarded loads -> two 8B uint2 stores
// (padA[x]=img[x-3], padB[x]=img[x-2]); 4 rows per block, 240 threads used.
__global__ __launch_bounds__(256) void k_setup(const float* __restrict__ w1,
                                               short* __restrict__ w1b,
                                               const float* __restrict__ w2,
                                               short* __restrict__ w2b,
                                               int2* __restrict__ map,
                                               float* __restrict__ stats,
                                               unsigned* __restrict__ h2p,
                                               const float* __restrict__ inp,
                                               short* __restrict__ padA,
                                               short* __restrict__ padB) {
    int blk = blockIdx.x;
    int tid = threadIdx.x;
    if (blk >= 2609) {                    // pad section: 96 planes x 59 row-groups
        int idx = blk - 2609;
        int pl = idx / 59, yg = idx - pl * 59;
        if (tid >= 240) return;
        int r4 = tid / 60, xi = tid - r4 * 60;
        int y = yg * 4 + r4;
        if (y >= PH) return;
        int x0 = xi * 4;
        int iy = y - 3;
        bool yok = (unsigned)iy < 224u;
        const float* src = inp + (size_t)pl * 50176 + iy * 224;
        float a[5];
#pragma unroll
        for (int k = 0; k < 5; k++) {
            int xx = x0 + k - 3;
            a[k] = (yok && (unsigned)xx < 224u) ? src[xx] : 0.f;
        }
        size_t o = (size_t)pl * PPL + y * PW + x0;
        uint2 ua, ub;
        ua.x = pack2bf(a[0], a[1]); ua.y = pack2bf(a[2], a[3]);
        ub.x = pack2bf(a[1], a[2]); ub.y = pack2bf(a[3], a[4]);
        *(uint2*)(padA + o) = ua;
        *(uint2*)(padB + o) = ub;
        return;
    }
    if (blk < 49) {
        int p = blk * 256 + tid;
        int oy = p / OUTSZ, ox = p % OUTSZ;
        int e = min(min(oy, ox), min(111 - oy, 111 - ox));
        int s = e >> 3;
        int a = 16 * s, b = a + 16, c = 224 - b, d = 224 - a;
        int ao = a >> 1, bo = b >> 1, co = c >> 1, dd = d >> 1;
        int ti, li, bi, ri;
        if      (oy >= ao && oy < bo && ox >= ao && ox < co) { ti=a; li=a; bi=b; ri=c; }
        else if (oy >= bo && oy < dd && ox >= ao && ox < bo) { ti=b; li=a; bi=d; ri=b; }
        else if (oy >= co && oy < dd && ox >= bo && ox < dd) { ti=c; li=b; bi=d; ri=d; }
        else                                                 { ti=a; li=c; bi=c; ri=d; }
        float scale = (float)(2.0 - (double)s * 0.16666666666666666);
        int tip = (int)((float)(ti + 6) / scale) - 3;
        int lip = (int)((float)(li + 6) / scale) - 3;
        int bip = (int)((float)(bi + 6) / scale) + 3;
        int rip = (int)((float)(ri + 6) / scale) + 3;
        int fh = (bip - tip - 7) / 2 + 1;
        int fw = (rip - lip - 7) / 2 + 1;
        int to = ti >> 1, lo = li >> 1, bo2 = bi >> 1, ro = ri >> 1;
        int i = oy - to, j = ox - lo;
        int pp = (i * fh) / (bo2 - to);
        int qq = (j * fw) / (ro - lo);
        map[p] = make_int2(tip + 2 * pp, lip + 2 * qq);
    } else if (blk < 145) {
        int idx = (blk - 49) * 256 + tid;
        int oc = idx / K1C, k = idx % K1C;
        int g8 = k >> 3, e2 = k & 7;
        float v = 0.f;
        if (g8 < 21 && e2 < 7) {
            int ic = g8 / 7, ky = g8 - ic * 7;
            v = w1[((oc * 3 + ic) * 7 + ky) * 7 + e2];
        }
        w1b[idx] = f2bf(v);
    } else if (blk < 721) {
        int idx = (blk - 145) * 256 + tid;      // input element of w2 (OIHW flat)
        int oc = idx / 1152;
        int rem = idx - oc * 1152;
        int ic = rem / 9;
        int s  = rem - ic * 9;
        int t  = s * 2 + (ic >> 6);             // K-step
        int ic6 = ic & 63;
        int slot = (ic6 >> 3) ^ (oc & 7);       // XOR-swizzled 16B chunk slot
        w2b[t * 8192 + oc * 64 + slot * 8 + (ic6 & 7)] = f2bf(w2[idx]);
    } else if (blk < 785) {
        stats[(blk - 721) * 256 + tid] = 0.f;
    } else {
        int idx = blk - 785;                  // 0..1823
        int bx = idx % 57, n = idx / 57;
        int c2 = tid & 63, po = tid >> 6;
        int pp = bx * 4 + po;                 // 0..227
        int y, x;
        if      (pp < 58)  { y = 0;  x = pp; }
        else if (pp < 116) { y = 57; x = pp - 58; }
        else if (pp < 172) { y = pp - 116 + 1; x = 0; }
        else               { y = pp - 172 + 1; x = 57; }
        h2p[(size_t)n * (HSTRIDE / 2) + (y * HP + x) * 64 + c2] = 0u;
    }
}

// ---------------------------------------------------------------------------
// conv1 (r4/r5-proven): wave = 64 oc x 32 px; block = 4 waves x 32 px = 128
// px on one 64-oc A-slice. A staged ONCE in LDS (32 KB, 16B-chunk XOR swizzle
// — measured-best layout); B = 12 up-front global 16B gathers. XCD n-chunked
// grid (pad gather L2-resident/XCD); 4 blocks/CU (the L2 write-combining
// sweet spot, r2/r5); DPP stats.
// r6 lesson: do NOT replace LDS staging with per-MFMA global loads — LDS is
// the latency decoupler (r6: 103 µs, VGPR 44, all pipes idle).
__global__ __launch_bounds__(256, 4) void k_conv1m(const short* __restrict__ padA,
                                                   const short* __restrict__ padB,
                                                   const short* __restrict__ w1b,
                                                   const int2* __restrict__ map,
                                                   short* __restrict__ out1b,
                                                   float* __restrict__ sum1x,
                                                   float* __restrict__ sq1x) {
    __shared__ short As[64 * 256];     // 32 KB: row r, 16B-chunk c at pos c^(r&15)
    __shared__ float sred[4][64][2];   // 2 KB
    int tid = threadIdx.x;
    int wave = tid >> 6, lane = tid & 63;
    int q = lane >> 4, l16 = lane & 15;
    // XCD-chunked id remap: 6272 = 8 XCD x 784; 784 = 4 images x 196 blocks.
    int id = blockIdx.x;
    int swz = (id & 7) * 784 + (id >> 3);
    int n = swz / 196;
    int x196 = swz - n * 196;
    int ochalf = x196 & 1;
    int pxblk = x196 >> 1;                            // 0..97
    int px0 = pxblk * 128 + wave * 32 + l16;
    int px1 = px0 + 16;
    int2 m0 = map[px0];
    int2 m1 = map[px1];
    size_t bn = (size_t)n * 3 * PPL;
    const short* r0 = ((m0.y & 1) ? padB + (m0.y - 1) : padA + m0.y) + bn + m0.x * PW;
    const short* r1 = ((m1.y & 1) ? padB + (m1.y - 1) : padA + m1.y) + bn + m1.x * PW;

    // Stage A: 64 rows x 24 chunks of 16B = 1536 chunks; 6 per thread.
    const short* wsl = w1b + ochalf * 64 * K1C;
#pragma unroll
    for (int i = 0; i < 6; i++) {
        int chunk = tid + i * 256;
        int r = chunk / 24, c = chunk - r * 24;
        u4a v = *(const u4a*)(wsl + r * K1C + c * 8);
        *(u4a*)(As + r * 256 + ((c ^ (r & 15)) * 8)) = v;
    }

    // B loads (up-front, in-order consumption)
    bf16x8 ld[12];
#pragma unroll
    for (int icc = 0; icc < 6; icc++) {
        int g8 = (icc == 5) ? 20 : (icc * 4 + q);
        int ic = (g8 >= 7) + (g8 >= 14);
        int ky = g8 - ic * 7;
        int off = ic * PPL + ky * PW;
        ld[icc * 2]     = ldb8(r0 + off);
        ld[icc * 2 + 1] = ldb8(r1 + off);
    }

    f32x4 acc[4][2];
#pragma unroll
    for (int t = 0; t < 4; t++) { acc[t][0] = (f32x4){0,0,0,0}; acc[t][1] = (f32x4){0,0,0,0}; }

    __syncthreads();

    const short* Abase = As + l16 * 256;   // + t*16*256 + swizzled chunk
#pragma unroll
    for (int icc = 0; icc < 6; icc++) {
        bf16x8 bf0 = ld[icc * 2];
        bf16x8 bf1 = ld[icc * 2 + 1];
        int pos = ((icc * 4 + q) ^ l16) * 8;
#pragma unroll
        for (int t = 0; t < 4; t++) {
            bf16x8 af = *(const bf16x8*)(Abase + t * 16 * 256 + pos);
            acc[t][0] = __builtin_amdgcn_mfma_f32_16x16x32_bf16(af, bf0, acc[t][0], 0, 0, 0);
            acc[t][1] = __builtin_amdgcn_mfma_f32_16x16x32_bf16(af, bf1, acc[t][1], 0, 0, 0);
        }
    }

    // epilogue: C layout col(px)=l16, row(oc_local)=q*4+r ; store NHWC bf16
    short* ob = out1b + ((size_t)(n * PIX1) + px0) * OCN + ochalf * 64 + q * 4;
#pragma unroll
    for (int t = 0; t < 4; t++) {
#pragma unroll
        for (int g = 0; g < 2; g++) {
            f32x4 a = acc[t][g];
            uint2 u;
            u.x = pack2bf(a[0], a[1]);
            u.y = pack2bf(a[2], a[3]);
            *(uint2*)(ob + (size_t)g * 16 * OCN + t * 16) = u;
        }
    }

    // fused BN1 stats: DPP 16-lane rowsum (VALU only) -> LDS -> block pass
#pragma unroll
    for (int t = 0; t < 4; t++) {
#pragma unroll
        for (int r = 0; r < 4; r++) {
            float a0 = acc[t][0][r], a1 = acc[t][1][r];
            float s = rowsum16(a0 + a1);
            float z = rowsum16(fmaf(a0, a0, a1 * a1));
            if (l16 == 0) {
                int ocl = t * 16 + q * 4 + r;     // 0..63
                sred[wave][ocl][0] = s;
                sred[wave][ocl][1] = z;
            }
        }
    }
    __syncthreads();
    if (tid < 64) {
        float s = sred[0][tid][0] + sred[1][tid][0] + sred[2][tid][0] + sred[3][tid][0];
        float z = sred[0][tid][1] + sred[1][tid][1] + sred[2][tid][1] + sred[3][tid][1];
        int oc = ochalf * 64 + tid;
        atomicAdd(&sum1x[n * OCN + oc], s);
        atomicAdd(&sq1x[n * OCN + oc], z);
    }
}

// ---------------------------------------------------------------------------
// Finalize BN params from per-n partial sums: 32x128 -> scale/shift.
__global__ void k_fin2(const float* __restrict__ sumx, const float* __restrict__ sqx,
                       const float* __restrict__ gamma, const float* __restrict__ beta,
                       float invN, float* __restrict__ scale, float* __restrict__ shift) {
    int c = threadIdx.x;
    if (c >= OCN) return;
    float s = 0.f, q = 0.f;
    for (int n = 0; n < BN_; n++) { s += sumx[n * OCN + c]; q += sqx[n * OCN + c]; }
    float m = s * invN;
    float v = q * invN - m * m;
    float sc = gamma[c] * rsqrtf(v + 1e-5f);
    scale[c] = sc;
    shift[c] = beta[c] - m * sc;
}

// ---------------------------------------------------------------------------
// BN1 affine + 3x3/2 maxpool + ReLU: NHWC bf16 (112x112) -> padded NHWC bf16
// (58x58). r5: uint2-vectorized (32 threads/px, 4 ch/thread, 8 px/block).
// r8: XCD-chunked 1D grid — each XCD owns 4 complete images with contiguous
// px-blocks, so the 3x3 row-overlap reads hit the XCD's own L2 instead of
// being re-fetched by up to 8 XCDs (same mechanism as conv1m's r4 fix).
__global__ __launch_bounds__(256) void k_bnpool(const uint2* __restrict__ out1b,
                                                const float* __restrict__ scale,
                                                const float* __restrict__ shift,
                                                uint2* __restrict__ h2p) {
    int tid = threadIdx.x;
    int c4 = tid & 31, po = tid >> 5;
    // 12544 = 8 XCD x 1568; 1568 = 4 images x 392 px-blocks.
    int id = blockIdx.x;
    int swz = (id & 7) * 1568 + (id >> 3);
    int n = swz / 392;
    int pb = swz - n * 392;
    int pp = pb * 8 + po;
    int py = pp / POOLSZ, px = pp % POOLSZ;
    const uint2* base = out1b + (size_t)n * PIX1 * 32;
    int c0 = c4 * 4;
    float4 sc = *(const float4*)(scale + c0);
    float4 sh = *(const float4*)(shift + c0);
    float m0 = -1e30f, m1 = -1e30f, m2 = -1e30f, m3 = -1e30f;
#pragma unroll
    for (int dy = 0; dy < 3; dy++) {
        int y = 2 * py - 1 + dy;
        if ((unsigned)y >= (unsigned)OUTSZ) continue;
#pragma unroll
        for (int dx = 0; dx < 3; dx++) {
            int x = 2 * px - 1 + dx;
            if ((unsigned)x >= (unsigned)OUTSZ) continue;
            uint2 u = base[(size_t)(y * OUTSZ + x) * 32 + c4];
            m0 = fmaxf(m0, fmaf(sc.x, __uint_as_float(u.x << 16), sh.x));
            m1 = fmaxf(m1, fmaf(sc.y, __uint_as_float(u.x & 0xffff0000u), sh.y));
            m2 = fmaxf(m2, fmaf(sc.z, __uint_as_float(u.y << 16), sh.z));
            m3 = fmaxf(m3, fmaf(sc.w, __uint_as_float(u.y & 0xffff0000u), sh.w));
        }
    }
    uint2 o;
    o.x = pack2bf(fmaxf(m0, 0.f), fmaxf(m1, 0.f));
    o.y = pack2bf(fmaxf(m2, 0.f), fmaxf(m3, 0.f));
    h2p[(size_t)n * (HSTRIDE / 4) + ((py + 1) * HP + (px + 1)) * 32 + c4] = o;
}

// ---------------------------------------------------------------------------
// conv2 (r1-proven, untouched): implicit GEMM, m97 structure. M=128 oc,
// N-tile=112 px (2 rows), BK=64 (18 K-steps). 4 waves, each 32 oc x 112 px.
// A (16 KB) + B (14 KB) single-buffer LDS via global_load_lds w=16; 2
// barriers/step; 4 blocks/CU. NHWC epilogue; DPP stats.
__global__ __launch_bounds__(256, 4) void k_conv2g(const short* __restrict__ h2p,
                                                   const short* __restrict__ w2b,
                                                   short* __restrict__ out2b,
                                                   float* __restrict__ sum2x,
                                                   float* __restrict__ sq2x) {
    __shared__ short LDSb[15360];          // A: [0,8192) shorts; B: [8192,15360)
    int tid = threadIdx.x;
    int wave = tid >> 6, lane = tid & 63;
    int q = lane >> 4, l16 = lane & 15;
    int id = blockIdx.x;                   // 0..895, XCD-major
    int xcd = id & 7, seq = id >> 3;       // seq 0..111
    int n = xcd + 8 * (seq / 28);
    int rb = seq % 28;
    int y0 = rb * 2;                       // output rows y0, y0+1
    const short* hb = h2p + (size_t)n * HSTRIDE;

    // B staging source offsets (elems, step-delta excluded)
    int bofs[4];
#pragma unroll
    for (int i = 0; i < 4; i++) {
        int ck = tid + i * 256;
        if (ck > 895) ck = 895;            // i==3, tid>=128: lanes inactive
        int px = ck >> 3, sl = ck & 7;
        int r = px >= 56;
        int xc = px - (r ? 56 : 0);
        bofs[i] = ((y0 + r) * 58 + xc) * 128 + ((sl ^ (px & 7)) * 8);
    }

    f32x4 acc[2][7];
#pragma unroll
    for (int t16 = 0; t16 < 2; t16++)
#pragma unroll
        for (int g = 0; g < 7; g++) acc[t16][g] = (f32x4){0, 0, 0, 0};

    const short* Az = LDSb;
    const short* Bz = LDSb + 8192;
    int arow0 = (wave * 32 + l16) * 64;
    int arow1 = arow0 + 16 * 64;

    for (int t = 0; t < 18; t++) {
        __syncthreads();                   // previous compute done in all waves
        // ---- stage A (4x16B/thread, linear) + B (3.5x16B/thread, pre-swz src)
        const short* wt = w2b + t * 8192;
#pragma unroll
        for (int i = 0; i < 4; i++)
            gload16(wt + (tid + i * 256) * 8, &LDSb[(tid + i * 256) * 8]);
        int s = t >> 1, ich = t & 1;
        int dy = s / 3, dx = s - dy * 3;
        int doff = (dy * 58 + dx) * 128 + ich * 64;
#pragma unroll
        for (int i = 0; i < 3; i++)
            gload16(hb + bofs[i] + doff, &LDSb[8192 + (tid + i * 256) * 8]);
        if (tid < 128)
            gload16(hb + bofs[3] + doff, &LDSb[8192 + (tid + 768) * 8]);
        asm volatile("s_waitcnt vmcnt(0)" ::: "memory");
        __syncthreads();
        // ---- compute: 2 k-sub x (2 A-frag reads + 7 B-frag reads + 14 MFMA)
#pragma unroll
        for (int icc2 = 0; icc2 < 2; icc2++) {
            int so = ((icc2 * 4 + q) ^ (l16 & 7)) * 8;
            bf16x8 af0 = *(const bf16x8*)(Az + arow0 + so);
            bf16x8 af1 = *(const bf16x8*)(Az + arow1 + so);
            bf16x8 bf[7];
#pragma unroll
            for (int g = 0; g < 7; g++)
                bf[g] = *(const bf16x8*)(Bz + (g * 16 + l16) * 64 + so);
#pragma unroll
            for (int g = 0; g < 7; g++) {
                acc[0][g] = __builtin_amdgcn_mfma_f32_16x16x32_bf16(af0, bf[g], acc[0][g], 0, 0, 0);
                acc[1][g] = __builtin_amdgcn_mfma_f32_16x16x32_bf16(af1, bf[g], acc[1][g], 0, 0, 0);
            }
        }
    }

    // ---- epilogue: C col(px)=l16, row(oc)=q*4+r ; store NHWC bf16 ----
    short* ob = out2b + ((size_t)n * PIX2 + y0 * 56) * OCN + wave * 32 + q * 4;
#pragma unroll
    for (int t16 = 0; t16 < 2; t16++) {
#pragma unroll
        for (int g = 0; g < 7; g++) {
            f32x4 a = acc[t16][g];
            uint2 u;
            u.x = pack2bf(a[0], a[1]);
            u.y = pack2bf(a[2], a[3]);
            *(uint2*)(ob + (size_t)(g * 16 + l16) * OCN + t16 * 16) = u;
        }
    }

    // ---- fused BN2 stats: DPP rowsum; waves own distinct oc -> atomics ----
#pragma unroll
    for (int t16 = 0; t16 < 2; t16++) {
#pragma unroll
        for (int r = 0; r < 4; r++) {
            float sv = 0.f, zv = 0.f;
#pragma unroll
            for (int g = 0; g < 7; g++) {
                float v = acc[t16][g][r];
                sv += v;
                zv = fmaf(v, v, zv);
            }
            sv = rowsum16(sv);
            zv = rowsum16(zv);
            if (l16 == 0) {
                int oc = wave * 32 + t16 * 16 + q * 4 + r;
                atomicAdd(&sum2x[n * OCN + oc], sv);
                atomicAdd(&sq2x[n * OCN + oc], zv);
            }
        }
    }
}

// ---------------------------------------------------------------------------
// BN2 affine + ReLU: NHWC bf16 out2b -> NCHW fp32 d_out.
// r7-proven: jc channel-group split across gridDim.y = 4 (1568 blocks).
__global__ __launch_bounds__(256) void k_bnrelu(const short* __restrict__ in2,
                                                float* __restrict__ y,
                                                const float* __restrict__ scale,
                                                const float* __restrict__ shift) {
    int tid = threadIdx.x;
    int w = tid >> 6, l = tid & 63;
    int jc = blockIdx.y;                                 // 0..3 channel group
    int pxg = blockIdx.x * 256 + w * 64 + (l & 15) * 4;  // wave spans 64 px (never crosses n)
    int n = pxg / PIX2;
    int px = pxg - n * PIX2;
    const short* src = in2 + (size_t)pxg * OCN + (l >> 4) * 8 + jc * 32;
    float* dst = y + (size_t)n * (OCN * PIX2) + px;
    int c0 = (l >> 4) * 8 + jc * 32;
    bf16x8 v0 = ldb8(src);
    bf16x8 v1 = ldb8(src + OCN);
    bf16x8 v2 = ldb8(src + 2 * OCN);
    bf16x8 v3 = ldb8(src + 3 * OCN);
#pragma unroll
    for (int j = 0; j < 8; j++) {
        float sc = scale[c0 + j], sh = shift[c0 + j];
        float4 o;
        o.x = fmaxf(fmaf(sc, bf2f(v0[j]), sh), 0.f);
        o.y = fmaxf(fmaf(sc, bf2f(v1[j]), sh), 0.f);
        o.z = fmaxf(fmaf(sc, bf2f(v2[j]), sh), 0.f);
        o.w = fmaxf(fmaf(sc, bf2f(v3[j]), sh), 0.f);
        *(float4*)(dst + (size_t)(c0 + j) * PIX2) = o;
    }
}

// ---------------------------------------------------------------------------
extern "C" void kernel_launch(void* const* d_in, const int* in_sizes, int n_in,
                              void* d_out, int out_size, void* d_ws, size_t ws_size,
                              hipStream_t stream) {
    const float* inp = (const float*)d_in[0];
    const float* w1  = (const float*)d_in[1];
    const float* g1  = (const float*)d_in[2];
    const float* b1  = (const float*)d_in[3];
    const float* w2  = (const float*)d_in[4];
    const float* g2  = (const float*)d_in[5];
    const float* b2  = (const float*)d_in[6];
    float* out = (float*)d_out;

    char* ws = (char*)d_ws;
    int2*  map   = (int2*)ws;                         // 100,352 B
    float* stats = (float*)(ws + 102400);             // 65,536 B zeroed in k_setup
    short* w2b   = (short*)(ws + 176128);             // 294,912 B -> 471,040
    short* w1b   = (short*)(ws + 471040);             // 49,152 B  -> 520,192
    short* padA  = (short*)(ws + 520192);             // 10,736,640 B -> 11,256,832
    short* padB  = (short*)(ws + 11256832ULL);        // 10,736,640 B -> 21,993,472
    short* h2p   = (short*)(ws + 21993472ULL);        // 27,557,888 B -> 49,551,360
    short* out1b = (short*)(ws + 49551360ULL);        // 102,760,448 B -> 152,311,808
    short* out2b = (short*)(ws + 152311808ULL);       // 25,690,112 B -> 178,001,920 (NHWC)

    float* sum1x = stats;                // 32*128
    float* sq1x  = stats + 4096;
    float* sum2x = stats + 8192;
    float* sq2x  = stats + 12288;
    float* SC1 = stats + 16384, *SH1 = stats + 16512;
    float* SC2 = stats + 16640, *SH2 = stats + 16768;

    k_setup <<<dim3(2609 + 96 * 59), 256, 0, stream>>>(w1, w1b, w2, w2b, map, stats,
                                                       (unsigned*)h2p, inp, padA, padB);
    k_conv1m<<<dim3(6272), 256, 0, stream>>>(padA, padB, w1b, map, out1b, sum1x, sq1x);
    k_fin2  <<<1, 128, 0, stream>>>(sum1x, sq1x, g1, b1, 1.f / (BN_ * PIX1), SC1, SH1);
    k_bnpool<<<dim3(12544), 256, 0, stream>>>((const uint2*)out1b, SC1, SH1, (uint2*)h2p);
    k_conv2g<<<dim3(896), 256, 0, stream>>>(h2p, w2b, out2b, sum2x, sq2x);
    k_fin2  <<<1, 128, 0, stream>>>(sum2x, sq2x, g2, b2, 1.f / (BN_ * PIX2), SC2, SH2);
    k_bnrelu<<<dim3(392, 4), 256, 0, stream>>>(out2b, out, SC2, SH2);
}